// Round 8
// baseline (110.873 us; speedup 1.0000x reference)
//
#include <hip/hip_runtime.h>

#define OC 1024
#define ICN 1024
#define KK 9
#define NELEM (OC * ICN * KK)
#define CH (ICN * KK)      // 9216 floats per channel
#define CH4 (CH / 4)       // 2304
#define BT 512             // stream kernel threads (8 waves)
#define KMB 1024           // kmax blocks
#define NROWS (OC * ICN)   // 1,048,576 rows
// ws layout (bytes): [0,4K) part | [4K,4K+4M) res | +4M prio | +4M meta
#define WS_NEED (4096 + 3 * NROWS * 4)

// ---------------- K1: per-block partial max -> ws array (no atomics) ----------------
__global__ void __launch_bounds__(256) kmax_part(const float* __restrict__ x,
                                                 float* __restrict__ part) {
    __shared__ float s_m[4];
    const int tid = blockIdx.x * 256 + threadIdx.x;
    const int stride = KMB * 256;  // float4 stride
    const float4* x4 = (const float4*)x;
    float m = 0.f;
    #pragma unroll
    for (int k = 0; k < 9; ++k) {  // 9 independent dwordx4 in flight
        float4 v = x4[tid + k * stride];
        m = fmaxf(m, fmaxf(fmaxf(fabsf(v.x), fabsf(v.y)), fmaxf(fabsf(v.z), fabsf(v.w))));
    }
    #pragma unroll
    for (int off = 32; off > 0; off >>= 1)
        m = fmaxf(m, __shfl_xor(m, off, 64));
    if ((threadIdx.x & 63) == 0) s_m[threadIdx.x >> 6] = m;
    __syncthreads();
    if (threadIdx.x == 0)
        part[blockIdx.x] = fmaxf(fmaxf(s_m[0], s_m[1]), fmaxf(s_m[2], s_m[3]));
}

// fallback if ws too small: single-u32 atomic
__global__ void __launch_bounds__(256) kmax_atomic(const float* __restrict__ x,
                                                   unsigned* __restrict__ ws) {
    __shared__ float s_m[4];
    const int tid = blockIdx.x * 256 + threadIdx.x;
    const int stride = KMB * 256;
    const float4* x4 = (const float4*)x;
    float m = 0.f;
    #pragma unroll
    for (int k = 0; k < 9; ++k) {
        float4 v = x4[tid + k * stride];
        m = fmaxf(m, fmaxf(fmaxf(fabsf(v.x), fabsf(v.y)), fmaxf(fabsf(v.z), fabsf(v.w))));
    }
    #pragma unroll
    for (int off = 32; off > 0; off >>= 1)
        m = fmaxf(m, __shfl_xor(m, off, 64));
    if ((threadIdx.x & 63) == 0) s_m[threadIdx.x >> 6] = m;
    __syncthreads();
    if (threadIdx.x == 0) {
        m = fmaxf(fmaxf(s_m[0], s_m[1]), fmaxf(s_m[2], s_m[3]));
        atomicMax(ws, __float_as_uint(m));
    }
}

// ---- DPP 64-lane sum (canonical GCN sequence); total lands in lane 63 ----
template <int C>
__device__ __forceinline__ unsigned dpp_add_step(unsigned v) {
    unsigned o = (unsigned)__builtin_amdgcn_update_dpp(0, (int)v, C, 0xF, 0xF, false);
    return v + o;
}
__device__ __forceinline__ unsigned wave_sum_u32(unsigned v) {
    v = dpp_add_step<0x111>(v);   // row_shr:1
    v = dpp_add_step<0x112>(v);   // row_shr:2
    v = dpp_add_step<0x114>(v);   // row_shr:4
    v = dpp_add_step<0x118>(v);   // row_shr:8  -> lane 15/31/47/63 hold row sums
    v = dpp_add_step<0x142>(v);   // row_bcast15
    v = dpp_add_step<0x143>(v);   // row_bcast31 -> lane 63 holds total
    return (unsigned)__builtin_amdgcn_readlane((int)v, 63);
}

// ---- shared: barrier-free global-scale reduce (redundant per wave, part L2-hot) ----
__device__ __forceinline__ float scale_from_part(const float* __restrict__ part, int t) {
    float m = 0.f;
    #pragma unroll
    for (int i = 0; i < 16; ++i) m = fmaxf(m, part[(t & 63) + i * 64]);
    #pragma unroll
    for (int off = 32; off > 0; off >>= 1)
        m = fmaxf(m, __shfl_xor(m, off, 64));
    return m / 127.0f;
}

// ---------------- K2a: pure-stream quantize + stage-1 flips (no LDS, no barriers) ---
// Each thread owns rows t and t+BT of its channel. Writes speculative dequant out
// and per-row res/prio/meta to workspace. Stage-1 math identical to R5/R7.
__global__ void __launch_bounds__(BT, 8) quant_stream(const float* __restrict__ x,
                                                      float* __restrict__ out,
                                                      const float* __restrict__ part,
                                                      float* __restrict__ g_res,
                                                      float* __restrict__ g_prio,
                                                      int* __restrict__ g_meta) {
    const int oc = blockIdx.x;
    const int t  = threadIdx.x;
    const long long ocbase = (long long)oc * CH;
    const int rowbase = oc * ICN;

    // prefetch both rows into registers (18 outstanding dword loads)
    const float* p0 = x + ocbase + (long long)t * KK;
    const float* p1 = p0 + (long long)BT * KK;
    float a0[KK], a1[KK];
    #pragma unroll
    for (int k = 0; k < KK; ++k) a0[k] = p0[k];
    #pragma unroll
    for (int k = 0; k < KK; ++k) a1[k] = p1[k];

    const float scale = scale_from_part(part, t);   // overlaps prefetch latency
    const float iscale = 1.0f / scale;  // mul instead of IEEE div: <=1ulp, bounded <=2 steps

    #pragma unroll
    for (int half = 0; half < 2; ++half) {
        const int row = t + half * BT;
        float rn[KK], re[KK];
        float e = 0.f;
        #pragma unroll
        for (int k = 0; k < KK; ++k) {
            float q = (half ? a1[k] : a0[k]) * iscale;
            q = fminf(fmaxf(q, -127.f), 127.f);
            float r = rintf(q);                 // round half to even
            rn[k] = r;
            re[k] = r - q;
            e += re[k];
        }
        int nf = (int)rintf(fabsf(e));
        bool up = e < 0.f;
        unsigned flipped = 0u;
        int bidx = -1;
        float b_re = 0.f;
        for (int f = 0; f < nf; ++f) {
            float bp = 0.f; int bk = -1; float cre = 0.f;
            #pragma unroll
            for (int k = 0; k < KK; ++k) {
                bool cand = up ? (re[k] < 0.f) : (re[k] > 0.f);
                float p = (cand && !((flipped >> k) & 1u)) ? fabsf(re[k]) : 0.f;
                if (p > bp) { bp = p; bk = k; cre = re[k]; }  // strict >: lowest idx wins ties
            }
            if (bk < 0) break;  // safety
            flipped |= (1u << bk);
            bidx = bk; b_re = cre;
        }
        int cnt = __popc(flipped);
        float sgn = up ? 1.f : -1.f;

        float* po = out + ocbase + (long long)row * KK;
        #pragma unroll
        for (int k = 0; k < KK; ++k) {
            float v = rn[k] + (((flipped >> k) & 1u) ? sgn : 0.f);
            po[k] = v * scale;                   // speculative dequant store
        }
        g_res[rowbase + row] = e + sgn * (float)cnt;
        if (bidx >= 0) {
            g_prio[rowbase + row] = fabsf(b_re + sgn);   // |re2| at boundary in [0.5,1]
            g_meta[rowbase + row] = (row * KK + bidx) | ((up ? 1 : 0) << 16);
        } else {
            g_prio[rowbase + row] = 0.f;
            g_meta[rowbase + row] = 0;
        }
    }
}

// ---------------- K2b: per-channel stage-2 fixup, one wave per channel --------------
// Reduction order over res is bit-identical to prior stage-2 (16/lane + butterfly).
// q recovered exactly from the speculative out: |v*scale*iscale - v| << 0.5.
__global__ void __launch_bounds__(64) fixup_kernel(const float* __restrict__ x,
                                                   float* __restrict__ out,
                                                   const float* __restrict__ part,
                                                   const float* __restrict__ g_res,
                                                   const float* __restrict__ g_prio,
                                                   const int* __restrict__ g_meta) {
    const int oc = blockIdx.x;
    const int t  = threadIdx.x;           // 0..63
    const long long ocbase = (long long)oc * CH;
    const int rowbase = oc * ICN;

    const float scale = scale_from_part(part, t);
    const float iscale = 1.0f / scale;

    float s = 0.f;
    #pragma unroll
    for (int i = 0; i < ICN / 64; ++i) s += g_res[rowbase + t + i * 64];
    #pragma unroll
    for (int off = 32; off > 0; off >>= 1) s += __shfl_xor(s, off, 64);

    int n2 = (int)rintf(fabsf(s));
    bool up2 = s < 0.f;
    if (n2 == 0) return;

    // Order-exact u32 key: p in [0.5,1.0] -> bits-0x3F000000+1 monotone,
    // <<4 | (15-i) tie-breaks to lower row; equal keys across lanes ->
    // lower lane via ballot rank. Matches reference stable argsort.
    unsigned k[ICN / 64];
    #pragma unroll
    for (int i = 0; i < ICN / 64; ++i) {
        int r = rowbase + t + i * 64;
        float pr = g_prio[r];
        int dir = g_meta[r] >> 16;        // 1: row flipped up -> stage-2 down candidate
        bool match = ((dir != 0) != up2);
        unsigned bits = __float_as_uint(pr);
        k[i] = (pr > 0.f && match)
                 ? (((bits - 0x3F000000u + 1u) << 4) | (15u - (unsigned)i))
                 : 0u;
    }

    unsigned cloc = 0u;
    #pragma unroll
    for (int i = 0; i < ICN / 64; ++i) cloc += (k[i] != 0u) ? 1u : 0u;
    unsigned Ctot = wave_sum_u32(cloc);

    int f = 0;
    if (Ctot > 0u) {
        unsigned nsel = ((unsigned)n2 < Ctot) ? (unsigned)n2 : Ctot;

        // T = nsel-th largest key: max T with count(key >= T) >= nsel. Keys < 2^28.
        unsigned T = 0u;
        for (int b = 27; b >= 0; --b) {
            unsigned cand = T | (1u << b);
            unsigned c = 0u;
            #pragma unroll
            for (int i = 0; i < ICN / 64; ++i) c += (k[i] >= cand) ? 1u : 0u;
            if (wave_sum_u32(c) >= nsel) T = cand;   // wave-uniform branch
        }

        unsigned c1loc = 0u;
        unsigned fmask = 0u;
        #pragma unroll
        for (int i = 0; i < ICN / 64; ++i) {
            if (k[i] > T) { fmask |= (1u << i); c1loc += 1u; }
        }
        unsigned C1 = wave_sum_u32(c1loc);
        int need = (int)nsel - (int)C1;   // >= 1 by construction of T

        int tie_i = -1;
        #pragma unroll
        for (int i = 0; i < ICN / 64; ++i) {
            if (k[i] == T) tie_i = i;
        }
        unsigned long long tmask = __ballot(tie_i >= 0);
        int rank = __popcll(tmask & ((1ull << t) - 1ull));
        if (tie_i >= 0 && rank < need) fmask |= (1u << tie_i);

        f = (int)nsel;

        // fix-up stores: only flipped gids (distinct rows -> distinct gids).
        // q = rint(out*iscale) recovers the exact small int (err <= 2.3e-5).
        #pragma unroll
        for (int i = 0; i < ICN / 64; ++i) {
            if ((fmask >> i) & 1u) {
                int meta = g_meta[rowbase + t + i * 64];
                int gid = meta & 0xFFFF;
                float qv = rintf(out[ocbase + gid] * iscale);
                float nq = qv + ((meta >> 16) ? -1.f : 1.f);
                out[ocbase + gid] = nq * scale;
            }
        }
    }

    // zero-priority overflow path (dead with this data; deviation <= 1 step)
    if (f < n2) {
        int remaining = n2 - f;
        if (remaining > CH) remaining = CH;
        for (int j = t; j < remaining; j += 64) {
            float q = x[ocbase + j] * iscale;
            q = fminf(fmaxf(q, -127.f), 127.f);
            float r = rintf(q);
            float rr = r - q;
            float v = up2 ? ((rr < 0.f) ? r + 1.f : r)
                          : ((rr > 0.f) ? r - 1.f : r);
            out[ocbase + j] = v * scale;
        }
    }
}

// ---------------- fallback: R7 fused squant (proven path, used when ws small) -------
__global__ void __launch_bounds__(BT, 8) squant_kernel(const float* __restrict__ x,
                                                       float* __restrict__ out,
                                                       const float* __restrict__ part,
                                                       int nparts) {
    __shared__ __align__(16) signed char s_q[CH];
    __shared__ float s_res[ICN];
    __shared__ float s_prio[ICN];
    __shared__ int   s_meta[ICN];

    const int oc = blockIdx.x;
    const int t  = threadIdx.x;
    const long long ocbase = (long long)oc * CH;

    const float* p0 = x + ocbase + (long long)t * KK;
    const float* p1 = p0 + (long long)BT * KK;
    float a0[KK], a1[KK];
    #pragma unroll
    for (int k = 0; k < KK; ++k) a0[k] = p0[k];
    #pragma unroll
    for (int k = 0; k < KK; ++k) a1[k] = p1[k];

    float m;
    if (nparts > 0) {
        m = scale_from_part(part, t) * 127.0f;
    } else {
        m = __uint_as_float(((const unsigned*)part)[0]);
    }
    const float scale = m / 127.0f;
    const float iscale = 1.0f / scale;

    #pragma unroll
    for (int half = 0; half < 2; ++half) {
        const int row = t + half * BT;
        float rn[KK], re[KK];
        float e = 0.f;
        #pragma unroll
        for (int k = 0; k < KK; ++k) {
            float q = (half ? a1[k] : a0[k]) * iscale;
            q = fminf(fmaxf(q, -127.f), 127.f);
            float r = rintf(q);
            rn[k] = r;
            re[k] = r - q;
            e += re[k];
        }
        int nf = (int)rintf(fabsf(e));
        bool up = e < 0.f;
        unsigned flipped = 0u;
        int bidx = -1;
        float b_re = 0.f;
        for (int f = 0; f < nf; ++f) {
            float bp = 0.f; int bk = -1; float cre = 0.f;
            #pragma unroll
            for (int k = 0; k < KK; ++k) {
                bool cand = up ? (re[k] < 0.f) : (re[k] > 0.f);
                float p = (cand && !((flipped >> k) & 1u)) ? fabsf(re[k]) : 0.f;
                if (p > bp) { bp = p; bk = k; cre = re[k]; }
            }
            if (bk < 0) break;
            flipped |= (1u << bk);
            bidx = bk; b_re = cre;
        }
        int cnt = __popc(flipped);
        float sgn = up ? 1.f : -1.f;

        float* po = out + ocbase + (long long)row * KK;
        #pragma unroll
        for (int k = 0; k < KK; ++k) {
            float v = rn[k] + (((flipped >> k) & 1u) ? sgn : 0.f);
            po[k] = v * scale;
            s_q[row * KK + k] = (signed char)(int)v;
        }
        s_res[row] = e + sgn * (float)cnt;
        if (bidx >= 0) {
            s_prio[row] = fabsf(b_re + sgn);
            s_meta[row] = (row * KK + bidx) | ((up ? 1 : 0) << 16);
        } else {
            s_prio[row] = 0.f;
            s_meta[row] = 0;
        }
    }
    __syncthreads();

    if (t < 64) {
        float s = 0.f;
        #pragma unroll
        for (int i = 0; i < ICN / 64; ++i) s += s_res[t + i * 64];
        #pragma unroll
        for (int off = 32; off > 0; off >>= 1) s += __shfl_xor(s, off, 64);

        int n2 = (int)rintf(fabsf(s));
        bool up2 = s < 0.f;
        if (n2 > 0) {
            unsigned k[ICN / 64];
            #pragma unroll
            for (int i = 0; i < ICN / 64; ++i) {
                int r = t + i * 64;
                float pr = s_prio[r];
                int dir = s_meta[r] >> 16;
                bool match = ((dir != 0) != up2);
                unsigned bits = __float_as_uint(pr);
                k[i] = (pr > 0.f && match)
                         ? (((bits - 0x3F000000u + 1u) << 4) | (15u - (unsigned)i))
                         : 0u;
            }
            unsigned cloc = 0u;
            #pragma unroll
            for (int i = 0; i < ICN / 64; ++i) cloc += (k[i] != 0u) ? 1u : 0u;
            unsigned Ctot = wave_sum_u32(cloc);

            int f = 0;
            if (Ctot > 0u) {
                unsigned nsel = ((unsigned)n2 < Ctot) ? (unsigned)n2 : Ctot;
                unsigned T = 0u;
                for (int b = 27; b >= 0; --b) {
                    unsigned cand = T | (1u << b);
                    unsigned c = 0u;
                    #pragma unroll
                    for (int i = 0; i < ICN / 64; ++i) c += (k[i] >= cand) ? 1u : 0u;
                    if (wave_sum_u32(c) >= nsel) T = cand;
                }
                unsigned c1loc = 0u;
                unsigned fmask = 0u;
                #pragma unroll
                for (int i = 0; i < ICN / 64; ++i) {
                    if (k[i] > T) { fmask |= (1u << i); c1loc += 1u; }
                }
                unsigned C1 = wave_sum_u32(c1loc);
                int need = (int)nsel - (int)C1;
                int tie_i = -1;
                #pragma unroll
                for (int i = 0; i < ICN / 64; ++i) {
                    if (k[i] == T) tie_i = i;
                }
                unsigned long long tmask = __ballot(tie_i >= 0);
                int rank = __popcll(tmask & ((1ull << t) - 1ull));
                if (tie_i >= 0 && rank < need) fmask |= (1u << tie_i);
                f = (int)nsel;
                #pragma unroll
                for (int i = 0; i < ICN / 64; ++i) {
                    if ((fmask >> i) & 1u) {
                        int meta = s_meta[t + i * 64];
                        int gid = meta & 0xFFFF;
                        int nq = (int)s_q[gid] + ((meta >> 16) ? -1 : 1);
                        out[ocbase + gid] = (float)nq * scale;
                    }
                }
            }
            if (f < n2) {
                int remaining = n2 - f;
                if (remaining > CH) remaining = CH;
                for (int j = t; j < remaining; j += 64) {
                    float q = x[ocbase + j] * iscale;
                    q = fminf(fmaxf(q, -127.f), 127.f);
                    float r = rintf(q);
                    float rr = r - q;
                    float v = up2 ? ((rr < 0.f) ? r + 1.f : r)
                                  : ((rr > 0.f) ? r - 1.f : r);
                    out[ocbase + j] = v * scale;
                }
            }
        }
    }
}

extern "C" void kernel_launch(void* const* d_in, const int* in_sizes, int n_in,
                              void* d_out, int out_size, void* d_ws, size_t ws_size,
                              hipStream_t stream) {
    const float* x = (const float*)d_in[0];
    float* out = (float*)d_out;
    if (ws_size >= (size_t)WS_NEED) {
        float* part  = (float*)d_ws;
        float* g_res = (float*)((char*)d_ws + 4096);
        float* g_prio = g_res + NROWS;
        int*   g_meta = (int*)(g_prio + NROWS);
        kmax_part<<<KMB, 256, 0, stream>>>(x, part);
        quant_stream<<<OC, BT, 0, stream>>>(x, out, part, g_res, g_prio, g_meta);
        fixup_kernel<<<OC, 64, 0, stream>>>(x, out, part, g_res, g_prio, g_meta);
    } else if (ws_size >= KMB * sizeof(float)) {
        float* part = (float*)d_ws;
        kmax_part<<<KMB, 256, 0, stream>>>(x, part);
        squant_kernel<<<OC, BT, 0, stream>>>(x, out, part, KMB);
    } else {
        unsigned* wsmax = (unsigned*)d_ws;
        hipMemsetAsync(d_ws, 0, 4, stream);  // ws re-poisoned 0xAA each launch
        kmax_atomic<<<KMB, 256, 0, stream>>>(x, wsmax);
        squant_kernel<<<OC, BT, 0, stream>>>(x, out, (const float*)d_ws, 0);
    }
}

// Round 9
// 103.656 us; speedup vs baseline: 1.0696x; 1.0696x over previous
//
#include <hip/hip_runtime.h>

#define OC 1024
#define ICN 1024
#define KK 9
#define NELEM (OC * ICN * KK)
#define CH (ICN * KK)      // 9216 floats per channel
#define CH4 (CH / 4)       // 2304
#define BT 512             // squant block threads (8 waves -> 4 blocks/CU)
#define KMB 1024           // kmax blocks

// 4-byte-aligned float4: rows live at 36 B offsets, so dwordx4 loads must not
// assume 16 B alignment (gfx9+ global vector loads require only dword align).
typedef float float4u __attribute__((ext_vector_type(4), aligned(4)));

// ---------------- K1: per-block partial max -> ws array (no atomics) ----------------
__global__ void __launch_bounds__(256) kmax_part(const float* __restrict__ x,
                                                 float* __restrict__ part) {
    __shared__ float s_m[4];
    const int tid = blockIdx.x * 256 + threadIdx.x;
    const int stride = KMB * 256;  // float4 stride
    const float4* x4 = (const float4*)x;
    float m = 0.f;
    #pragma unroll
    for (int k = 0; k < 9; ++k) {  // 9 independent dwordx4 in flight
        float4 v = x4[tid + k * stride];
        m = fmaxf(m, fmaxf(fmaxf(fabsf(v.x), fabsf(v.y)), fmaxf(fabsf(v.z), fabsf(v.w))));
    }
    #pragma unroll
    for (int off = 32; off > 0; off >>= 1)
        m = fmaxf(m, __shfl_xor(m, off, 64));
    if ((threadIdx.x & 63) == 0) s_m[threadIdx.x >> 6] = m;
    __syncthreads();
    if (threadIdx.x == 0)
        part[blockIdx.x] = fmaxf(fmaxf(s_m[0], s_m[1]), fmaxf(s_m[2], s_m[3]));
}

// fallback if ws too small: single-u32 atomic
__global__ void __launch_bounds__(256) kmax_atomic(const float* __restrict__ x,
                                                   unsigned* __restrict__ ws) {
    __shared__ float s_m[4];
    const int tid = blockIdx.x * 256 + threadIdx.x;
    const int stride = KMB * 256;
    const float4* x4 = (const float4*)x;
    float m = 0.f;
    #pragma unroll
    for (int k = 0; k < 9; ++k) {
        float4 v = x4[tid + k * stride];
        m = fmaxf(m, fmaxf(fmaxf(fabsf(v.x), fabsf(v.y)), fmaxf(fabsf(v.z), fabsf(v.w))));
    }
    #pragma unroll
    for (int off = 32; off > 0; off >>= 1)
        m = fmaxf(m, __shfl_xor(m, off, 64));
    if ((threadIdx.x & 63) == 0) s_m[threadIdx.x >> 6] = m;
    __syncthreads();
    if (threadIdx.x == 0) {
        m = fmaxf(fmaxf(s_m[0], s_m[1]), fmaxf(s_m[2], s_m[3]));
        atomicMax(ws, __float_as_uint(m));
    }
}

// ---- DPP 64-lane sum (canonical GCN sequence); total lands in lane 63 ----
template <int C>
__device__ __forceinline__ unsigned dpp_add_step(unsigned v) {
    unsigned o = (unsigned)__builtin_amdgcn_update_dpp(0, (int)v, C, 0xF, 0xF, false);
    return v + o;
}
__device__ __forceinline__ unsigned wave_sum_u32(unsigned v) {
    v = dpp_add_step<0x111>(v);   // row_shr:1
    v = dpp_add_step<0x112>(v);   // row_shr:2
    v = dpp_add_step<0x114>(v);   // row_shr:4
    v = dpp_add_step<0x118>(v);   // row_shr:8  -> lane 15/31/47/63 hold row sums
    v = dpp_add_step<0x142>(v);   // row_bcast15
    v = dpp_add_step<0x143>(v);   // row_bcast31 -> lane 63 holds total
    return (unsigned)__builtin_amdgcn_readlane((int)v, 63);
}

// ---------------- K2: fused quant + stage1 + stage2, 512 thr ------------------------
// R7 structure (speculative store + fixup). This round: vectorized row I/O —
// dwordx4+dwordx4+dword per row instead of 9 scalar dwords, both load and store
// (line-visit amplification 648 -> 216 per wave-row-pair).
__global__ void __launch_bounds__(BT, 8) squant_kernel(const float* __restrict__ x,
                                                       float* __restrict__ out,
                                                       const float* __restrict__ part,
                                                       int nparts) {
    __shared__ __align__(16) signed char s_q[CH];     // 9 KB quant values (in [-127,127])
    __shared__ float s_res[ICN];   // per-row residual sum(re2)
    __shared__ float s_prio[ICN];  // boundary priority (0 if none)
    __shared__ int   s_meta[ICN];  // (dir<<16) | channel-local element idx

    const int oc = blockIdx.x;
    const int t  = threadIdx.x;
    const long long ocbase = (long long)oc * CH;

    // ---- prefetch both rows into registers: 3 loads per row (x4,x4,x1) ----
    const float* p0 = x + ocbase + (long long)t * KK;
    const float* p1 = p0 + (long long)BT * KK;
    float4u v00 = ((const float4u*)p0)[0];
    float4u v01 = ((const float4u*)p0)[1];
    float   v08 = p0[8];
    float4u v10 = ((const float4u*)p1)[0];
    float4u v11 = ((const float4u*)p1)[1];
    float   v18 = p1[8];

    // ---- scale phase, barrier-free (overlaps the prefetch latency) ----
    float m;
    if (nparts > 0) {
        m = 0.f;
        #pragma unroll
        for (int i = 0; i < 16; ++i) m = fmaxf(m, part[(t & 63) + i * 64]);
        #pragma unroll
        for (int off = 32; off > 0; off >>= 1)
            m = fmaxf(m, __shfl_xor(m, off, 64));
    } else {
        m = __uint_as_float(((const unsigned*)part)[0]);  // same-address broadcast
    }
    const float scale = m / 127.0f;
    const float iscale = 1.0f / scale;  // mul instead of IEEE div: <=1ulp on q, bounded <=2 steps

    // ---- stage 1: two rows from registers; vectorized speculative store ----
    #pragma unroll
    for (int half = 0; half < 2; ++half) {
        const int row = t + half * BT;
        float a[KK];
        if (half == 0) {
            a[0]=v00.x; a[1]=v00.y; a[2]=v00.z; a[3]=v00.w;
            a[4]=v01.x; a[5]=v01.y; a[6]=v01.z; a[7]=v01.w; a[8]=v08;
        } else {
            a[0]=v10.x; a[1]=v10.y; a[2]=v10.z; a[3]=v10.w;
            a[4]=v11.x; a[5]=v11.y; a[6]=v11.z; a[7]=v11.w; a[8]=v18;
        }
        float rn[KK], re[KK];
        float e = 0.f;
        #pragma unroll
        for (int k = 0; k < KK; ++k) {
            float q = a[k] * iscale;
            q = fminf(fmaxf(q, -127.f), 127.f);
            float r = rintf(q);                 // round half to even
            rn[k] = r;
            re[k] = r - q;
            e += re[k];
        }
        int nf = (int)rintf(fabsf(e));
        bool up = e < 0.f;
        unsigned flipped = 0u;
        int bidx = -1;
        float b_re = 0.f;
        for (int f = 0; f < nf; ++f) {
            float bp = 0.f; int bk = -1; float cre = 0.f;
            #pragma unroll
            for (int k = 0; k < KK; ++k) {
                bool cand = up ? (re[k] < 0.f) : (re[k] > 0.f);
                float p = (cand && !((flipped >> k) & 1u)) ? fabsf(re[k]) : 0.f;
                if (p > bp) { bp = p; bk = k; cre = re[k]; }  // strict >: lowest idx wins ties
            }
            if (bk < 0) break;  // safety
            flipped |= (1u << bk);
            bidx = bk; b_re = cre;
        }
        int cnt = __popc(flipped);
        float sgn = up ? 1.f : -1.f;

        float o[KK];
        #pragma unroll
        for (int k = 0; k < KK; ++k) {
            float v = rn[k] + (((flipped >> k) & 1u) ? sgn : 0.f);
            o[k] = v * scale;                    // speculative dequant value
            s_q[row * KK + k] = (signed char)(int)v;   // exact small int (fix-up source)
        }
        float* po = out + ocbase + (long long)row * KK;
        float4u s0; s0.x=o[0]; s0.y=o[1]; s0.z=o[2]; s0.w=o[3];
        float4u s1; s1.x=o[4]; s1.y=o[5]; s1.z=o[6]; s1.w=o[7];
        ((float4u*)po)[0] = s0;
        ((float4u*)po)[1] = s1;
        po[8] = o[8];

        s_res[row] = e + sgn * (float)cnt;
        if (bidx >= 0) {
            s_prio[row] = fabsf(b_re + sgn);     // |re2| at boundary in [0.5,1]
            s_meta[row] = (row * KK + bidx) | ((up ? 1 : 0) << 16);
        } else {
            s_prio[row] = 0.f;
            s_meta[row] = 0;
        }
    }
    __syncthreads();   // drains vmcnt(0): all stage-1 stores ordered before fix-ups

    // ---- stage 2: wave 0 only; exact top-n2 via 28-bit threshold binary search ----
    if (t < 64) {
        float s = 0.f;
        #pragma unroll
        for (int i = 0; i < ICN / 64; ++i) s += s_res[t + i * 64];
        #pragma unroll
        for (int off = 32; off > 0; off >>= 1) s += __shfl_xor(s, off, 64);

        int n2 = (int)rintf(fabsf(s));
        bool up2 = s < 0.f;
        if (n2 > 0) {
            // Order-exact u32 key: p in [0.5,1.0] -> bits-0x3F000000+1 monotone,
            // <<4 | (15-i) tie-breaks to lower row; equal keys across lanes ->
            // lower lane via ballot rank. Matches reference stable argsort.
            unsigned k[ICN / 64];
            #pragma unroll
            for (int i = 0; i < ICN / 64; ++i) {
                int r = t + i * 64;
                float pr = s_prio[r];
                int dir = s_meta[r] >> 16;       // 1: row flipped up -> stage-2 down candidate
                bool match = ((dir != 0) != up2);
                unsigned bits = __float_as_uint(pr);
                k[i] = (pr > 0.f && match)
                         ? (((bits - 0x3F000000u + 1u) << 4) | (15u - (unsigned)i))
                         : 0u;
            }

            unsigned cloc = 0u;
            #pragma unroll
            for (int i = 0; i < ICN / 64; ++i) cloc += (k[i] != 0u) ? 1u : 0u;
            unsigned Ctot = wave_sum_u32(cloc);

            int f = 0;
            if (Ctot > 0u) {
                unsigned nsel = ((unsigned)n2 < Ctot) ? (unsigned)n2 : Ctot;

                // T = nsel-th largest key: max T with count(key >= T) >= nsel.
                unsigned T = 0u;
                for (int b = 27; b >= 0; --b) {
                    unsigned cand = T | (1u << b);
                    unsigned c = 0u;
                    #pragma unroll
                    for (int i = 0; i < ICN / 64; ++i) c += (k[i] >= cand) ? 1u : 0u;
                    if (wave_sum_u32(c) >= nsel) T = cand;   // wave-uniform branch
                }

                unsigned c1loc = 0u;
                unsigned fmask = 0u;
                #pragma unroll
                for (int i = 0; i < ICN / 64; ++i) {
                    if (k[i] > T) { fmask |= (1u << i); c1loc += 1u; }
                }
                unsigned C1 = wave_sum_u32(c1loc);
                int need = (int)nsel - (int)C1;   // >= 1 by construction of T

                int tie_i = -1;
                #pragma unroll
                for (int i = 0; i < ICN / 64; ++i) {
                    if (k[i] == T) tie_i = i;
                }
                unsigned long long tmask = __ballot(tie_i >= 0);
                int rank = __popcll(tmask & ((1ull << t) - 1ull));
                if (tie_i >= 0 && rank < need) fmask |= (1u << tie_i);

                f = (int)nsel;

                // fix-up stores: only the flipped gids (distinct rows -> distinct gids).
                // (float)(q±1)*scale is bit-identical to the old stage-out path.
                #pragma unroll
                for (int i = 0; i < ICN / 64; ++i) {
                    if ((fmask >> i) & 1u) {
                        int meta = s_meta[t + i * 64];
                        int gid = meta & 0xFFFF;
                        int nq = (int)s_q[gid] + ((meta >> 16) ? -1 : 1);
                        out[ocbase + gid] = (float)nq * scale;
                    }
                }
            }

            // zero-priority overflow path (dead with this data; deviation <= 1 step)
            if (f < n2) {
                int remaining = n2 - f;
                if (remaining > CH) remaining = CH;
                for (int j = t; j < remaining; j += 64) {
                    float q = x[ocbase + j] * iscale;
                    q = fminf(fmaxf(q, -127.f), 127.f);
                    float r = rintf(q);
                    float rr = r - q;
                    float v = up2 ? ((rr < 0.f) ? r + 1.f : r)
                                  : ((rr > 0.f) ? r - 1.f : r);
                    out[ocbase + j] = v * scale;
                }
            }
        }
    }
    // no trailing barrier / stage-out: all output already in flight
}

extern "C" void kernel_launch(void* const* d_in, const int* in_sizes, int n_in,
                              void* d_out, int out_size, void* d_ws, size_t ws_size,
                              hipStream_t stream) {
    const float* x = (const float*)d_in[0];
    float* out = (float*)d_out;
    if (ws_size >= KMB * sizeof(float)) {
        float* part = (float*)d_ws;
        kmax_part<<<KMB, 256, 0, stream>>>(x, part);
        squant_kernel<<<OC, BT, 0, stream>>>(x, out, part, KMB);
    } else {
        unsigned* wsmax = (unsigned*)d_ws;
        hipMemsetAsync(d_ws, 0, 4, stream);  // ws re-poisoned 0xAA each launch
        kmax_atomic<<<KMB, 256, 0, stream>>>(x, wsmax);
        squant_kernel<<<OC, BT, 0, stream>>>(x, out, (const float*)d_ws, 0);
    }
}